// Round 1
// baseline (219.572 us; speedup 1.0000x reference)
//
#include <hip/hip_runtime.h>

// Problem constants (B=1, L=2048, E=512, H=8, D=64)
constexpr int L_SEQ = 2048;
constexpr int E_DIM = 512;
constexpr int H_NUM = 8;
constexpr int D_DIM = 64;
constexpr int QKV_W = 3 * E_DIM;   // 1536
constexpr int CHK = 64;            // chunk length
constexpr int NC = L_SEQ / CHK;    // 32 chunks
constexpr float PI_HALF = 1.5707963267948966f;

// ---------------------------------------------------------------------------
// Generic fp32 GEMM with bias:  C[M,N] = A[M,K] @ B[K,N] + bias[N]
// BM=64 rows, BN cols, BK=16, microtile TM x 4, threads = (64/TM)*(BN/4)
// ---------------------------------------------------------------------------
template <int BN, int TM>
__global__ __launch_bounds__((64 / TM) * (BN / 4)) void gemm_bias_f32(
    const float* __restrict__ A, const float* __restrict__ B,
    const float* __restrict__ bias, float* __restrict__ Cm,
    int M, int N, int K) {
  constexpr int NT = (64 / TM) * (BN / 4);
  constexpr int BNP = BN + 4;  // row stride pad; (BN+4)*4 bytes stays 16B aligned
  __shared__ float As[16][68];   // As[k][r] (transposed A tile), 68*4=272 -> 16B-aligned rows
  __shared__ float Bs[16][BNP];  // Bs[k][c]

  const int t = threadIdx.x;
  const int tx = t % (BN / 4);
  const int ty = t / (BN / 4);
  const int row0 = blockIdx.y * 64;
  const int col0 = blockIdx.x * BN;

  float acc[TM][4];
#pragma unroll
  for (int m = 0; m < TM; ++m)
#pragma unroll
    for (int n = 0; n < 4; ++n) acc[m][n] = 0.f;

  for (int k0 = 0; k0 < K; k0 += 16) {
    // Load A tile 64x16 (256 float4), store transposed into As[k][r]
    for (int idx4 = t; idx4 < 256; idx4 += NT) {
      const int r = idx4 >> 2;
      const int kq = (idx4 & 3) * 4;
      const float4 a = *(const float4*)&A[(size_t)(row0 + r) * K + k0 + kq];
      As[kq + 0][r] = a.x;
      As[kq + 1][r] = a.y;
      As[kq + 2][r] = a.z;
      As[kq + 3][r] = a.w;
    }
    // Load B tile 16xBN
    for (int idx4 = t; idx4 < 16 * (BN / 4); idx4 += NT) {
      const int kk = idx4 / (BN / 4);
      const int cq = (idx4 % (BN / 4)) * 4;
      *(float4*)&Bs[kk][cq] = *(const float4*)&B[(size_t)(k0 + kk) * N + col0 + cq];
    }
    __syncthreads();
#pragma unroll
    for (int kk = 0; kk < 16; ++kk) {
      float av[TM], bv[4];
#pragma unroll
      for (int m = 0; m < TM; m += 4) {
        const float4 a4 = *(const float4*)&As[kk][ty * TM + m];
        av[m] = a4.x; av[m + 1] = a4.y; av[m + 2] = a4.z; av[m + 3] = a4.w;
      }
      {
        const float4 b4 = *(const float4*)&Bs[kk][tx * 4];
        bv[0] = b4.x; bv[1] = b4.y; bv[2] = b4.z; bv[3] = b4.w;
      }
#pragma unroll
      for (int m = 0; m < TM; ++m)
#pragma unroll
        for (int n = 0; n < 4; ++n) acc[m][n] += av[m] * bv[n];
    }
    __syncthreads();
  }

  const float4 bb = *(const float4*)&bias[col0 + tx * 4];
#pragma unroll
  for (int m = 0; m < TM; ++m) {
    const int r = row0 + ty * TM + m;
    float4 o;
    o.x = acc[m][0] + bb.x;
    o.y = acc[m][1] + bb.y;
    o.z = acc[m][2] + bb.z;
    o.w = acc[m][3] + bb.w;
    *(float4*)&Cm[(size_t)r * N + col0 + tx * 4] = o;
  }
}

// ---------------------------------------------------------------------------
// Kernel A: per-(head, chunk) KV state sums.
//   S[h][c][d][e]      (d<64: cos part; d in [64,128): sin part) = sum_i phi_k * v
//   ksum[h][c][d1]     = sum_i phi_k[i][d1]
// ---------------------------------------------------------------------------
__global__ __launch_bounds__(256) void chunk_kv_kernel(
    const float* __restrict__ qkv, float* __restrict__ S, float* __restrict__ ksum) {
  const int c = blockIdx.x, h = blockIdx.y;
  __shared__ float kc[64][64];   // relu(k)*cos(th_i)  [i][d]
  __shared__ float ksn[64][64];  // relu(k)*sin(th_i)
  __shared__ float vs[64][64];   // v                  [i][e]
  __shared__ float cwA[64], swA[64];
  const int t = threadIdx.x;

  for (int idx = t; idx < 4096; idx += 256) {
    const int i = idx >> 6, d = idx & 63;
    const float* row = qkv + (size_t)(c * 64 + i) * QKV_W;
    kc[i][d] = fmaxf(row[E_DIM + h * 64 + d], 0.f);
    vs[i][d] = row[2 * E_DIM + h * 64 + d];
  }
  if (t < 64) {
    const int l = c * 64 + t;
    const float th = PI_HALF * (float)l / (float)L_SEQ;
    cwA[t] = cosf(th);
    swA[t] = sinf(th);
  }
  __syncthreads();
  for (int idx = t; idx < 4096; idx += 256) {
    const int i = idx >> 6, d = idx & 63;
    const float kv_ = kc[i][d];
    ksn[i][d] = kv_ * swA[i];
    kc[i][d] = kv_ * cwA[i];
  }
  __syncthreads();

  // GEMM: S_cos[d][e] = sum_i kc[i][d]*vs[i][e]; S_sin likewise. 4x4 microtile.
  const int tx = t & 15, ty = t >> 4;
  float acc_c[4][4], acc_s[4][4];
#pragma unroll
  for (int m = 0; m < 4; ++m)
#pragma unroll
    for (int n = 0; n < 4; ++n) { acc_c[m][n] = 0.f; acc_s[m][n] = 0.f; }

  for (int i = 0; i < 64; ++i) {
    const float4 ac = *(const float4*)&kc[i][ty * 4];
    const float4 as = *(const float4*)&ksn[i][ty * 4];
    const float4 b4 = *(const float4*)&vs[i][tx * 4];
    const float avc[4] = {ac.x, ac.y, ac.z, ac.w};
    const float avs[4] = {as.x, as.y, as.z, as.w};
    const float bv[4] = {b4.x, b4.y, b4.z, b4.w};
#pragma unroll
    for (int m = 0; m < 4; ++m)
#pragma unroll
      for (int n = 0; n < 4; ++n) {
        acc_c[m][n] += avc[m] * bv[n];
        acc_s[m][n] += avs[m] * bv[n];
      }
  }

  float* Sc = S + ((size_t)(h * NC + c)) * 8192;
#pragma unroll
  for (int m = 0; m < 4; ++m) {
    const int d = ty * 4 + m;
    float4 oc, os;
    oc.x = acc_c[m][0]; oc.y = acc_c[m][1]; oc.z = acc_c[m][2]; oc.w = acc_c[m][3];
    os.x = acc_s[m][0]; os.y = acc_s[m][1]; os.z = acc_s[m][2]; os.w = acc_s[m][3];
    *(float4*)&Sc[(size_t)d * 64 + tx * 4] = oc;
    *(float4*)&Sc[(size_t)(64 + d) * 64 + tx * 4] = os;
  }

  if (t < 64) {
    float sc = 0.f, ss = 0.f;
    for (int i = 0; i < 64; ++i) { sc += kc[i][t]; ss += ksn[i][t]; }
    float* Kc = ksum + (size_t)(h * NC + c) * 128;
    Kc[t] = sc;
    Kc[64 + t] = ss;
  }
}

// ---------------------------------------------------------------------------
// Kernel B: exclusive prefix scan over chunks (per head, per state element).
// grid: (32 element-groups of 256, 8 heads)
// ---------------------------------------------------------------------------
__global__ __launch_bounds__(256) void scan_kernel(
    const float* __restrict__ S, float* __restrict__ Sp,
    const float* __restrict__ ksum, float* __restrict__ ksumP) {
  const int h = blockIdx.y;
  const int e = blockIdx.x * 256 + threadIdx.x;  // 0..8191
  float run = 0.f;
  for (int c = 0; c < NC; ++c) {
    const size_t off = ((size_t)(h * NC + c)) * 8192 + e;
    Sp[off] = run;
    run += S[off];
  }
  if (blockIdx.x == 0 && threadIdx.x < 128) {
    const int d = threadIdx.x;
    float r2 = 0.f;
    for (int c = 0; c < NC; ++c) {
      const size_t off = (size_t)(h * NC + c) * 128 + d;
      ksumP[off] = r2;
      r2 += ksum[off];
    }
  }
}

// ---------------------------------------------------------------------------
// Kernel C: per-(head, chunk) output.
//   ctx[i][e] = cw[i]*sum_d q'[i][d]*Sp_cos[d][e] + sw[i]*sum_d q'[i][d]*Sp_sin[d][e]
//             + sum_{j<=i} A[i][j]*v[j][e],   A[i][j]=(q'[i]·k'[j])*(cw_i cw_j + sw_i sw_j)
//   nrm[i]   = cw[i]*(q'[i]·ksumP_cos) + sw[i]*(q'[i]·ksumP_sin) + sum_{j<=i} A[i][j]
//   attn[l][h*64+e] = ctx / (nrm + 1e-6)
// ---------------------------------------------------------------------------
__global__ __launch_bounds__(256) void chunk_out_kernel(
    const float* __restrict__ qkv, const float* __restrict__ Sp,
    const float* __restrict__ ksumP, float* __restrict__ attn) {
  const int c = blockIdx.x, h = blockIdx.y;
  __shared__ float qs[64][65];   // relu(q) [i][d], padded
  __shared__ float ksA[64][65];  // relu(k) [j][d], later A[i][j]
  __shared__ float vs[64][64];   // v [j][e]
  __shared__ float cwA[64], swA[64], nrmA[64];
  const int t = threadIdx.x;

  for (int idx = t; idx < 4096; idx += 256) {
    const int i = idx >> 6, d = idx & 63;
    const float* row = qkv + (size_t)(c * 64 + i) * QKV_W;
    qs[i][d] = fmaxf(row[h * 64 + d], 0.f);
    ksA[i][d] = fmaxf(row[E_DIM + h * 64 + d], 0.f);
    vs[i][d] = row[2 * E_DIM + h * 64 + d];
  }
  if (t < 64) {
    const int l = c * 64 + t;
    const float th = PI_HALF * (float)l / (float)L_SEQ;
    cwA[t] = cosf(th);
    swA[t] = sinf(th);
  }
  __syncthreads();

  const int tx = t & 15, ty = t >> 4;
  // A[i][j] for i=ty*4+m, j=tx*4+n (causal masked), into registers first
  float areg[4][4];
  {
    float acc[4][4];
#pragma unroll
    for (int m = 0; m < 4; ++m)
#pragma unroll
      for (int n = 0; n < 4; ++n) acc[m][n] = 0.f;
    for (int d = 0; d < 64; ++d) {
      float av[4], bv[4];
#pragma unroll
      for (int m = 0; m < 4; ++m) av[m] = qs[ty * 4 + m][d];
#pragma unroll
      for (int n = 0; n < 4; ++n) bv[n] = ksA[tx * 4 + n][d];
#pragma unroll
      for (int m = 0; m < 4; ++m)
#pragma unroll
        for (int n = 0; n < 4; ++n) acc[m][n] += av[m] * bv[n];
    }
#pragma unroll
    for (int m = 0; m < 4; ++m)
#pragma unroll
      for (int n = 0; n < 4; ++n) {
        const int i = ty * 4 + m, j = tx * 4 + n;
        const float w = cwA[i] * cwA[j] + swA[i] * swA[j];
        areg[m][n] = (j <= i) ? acc[m][n] * w : 0.f;
      }
  }
  __syncthreads();
#pragma unroll
  for (int m = 0; m < 4; ++m)
#pragma unroll
    for (int n = 0; n < 4; ++n) ksA[ty * 4 + m][tx * 4 + n] = areg[m][n];
  __syncthreads();

  // nrm per row (wave 0)
  if (t < 64) {
    const int i = t;
    const float* Kp = ksumP + (size_t)(h * NC + c) * 128;
    float s1 = 0.f, s2 = 0.f;
    for (int d = 0; d < 64; ++d) {
      const float q = qs[i][d];
      s1 += q * Kp[d];
      s2 += q * Kp[64 + d];
    }
    float s = cwA[i] * s1 + swA[i] * s2;
    for (int j = 0; j <= i; ++j) s += ksA[i][j];
    nrmA[i] = s;
  }
  __syncthreads();

  // ctx: inter (Sp from global, L1/L2 cached) + intra (A @ v)
  const float* Sc = Sp + ((size_t)(h * NC + c)) * 8192;
  float acc1[4][4], acc2[4][4], acc3[4][4];
#pragma unroll
  for (int m = 0; m < 4; ++m)
#pragma unroll
    for (int n = 0; n < 4; ++n) { acc1[m][n] = 0.f; acc2[m][n] = 0.f; acc3[m][n] = 0.f; }

  for (int d = 0; d < 64; ++d) {
    float av[4];
#pragma unroll
    for (int m = 0; m < 4; ++m) av[m] = qs[ty * 4 + m][d];
    const float4 b1 = *(const float4*)&Sc[(size_t)d * 64 + tx * 4];
    const float4 b2 = *(const float4*)&Sc[(size_t)(64 + d) * 64 + tx * 4];
    const float bv1[4] = {b1.x, b1.y, b1.z, b1.w};
    const float bv2[4] = {b2.x, b2.y, b2.z, b2.w};
#pragma unroll
    for (int m = 0; m < 4; ++m)
#pragma unroll
      for (int n = 0; n < 4; ++n) {
        acc1[m][n] += av[m] * bv1[n];
        acc2[m][n] += av[m] * bv2[n];
      }
  }
  for (int j = 0; j < 64; ++j) {
    float av[4];
#pragma unroll
    for (int m = 0; m < 4; ++m) av[m] = ksA[ty * 4 + m][j];
    const float4 b4 = *(const float4*)&vs[j][tx * 4];
    const float bv[4] = {b4.x, b4.y, b4.z, b4.w};
#pragma unroll
    for (int m = 0; m < 4; ++m)
#pragma unroll
      for (int n = 0; n < 4; ++n) acc3[m][n] += av[m] * bv[n];
  }

#pragma unroll
  for (int m = 0; m < 4; ++m) {
    const int i = ty * 4 + m;
    const float inv = 1.0f / (nrmA[i] + 1e-6f);
    const float cw = cwA[i], sw = swA[i];
    float4 o;
    o.x = (cw * acc1[m][0] + sw * acc2[m][0] + acc3[m][0]) * inv;
    o.y = (cw * acc1[m][1] + sw * acc2[m][1] + acc3[m][1]) * inv;
    o.z = (cw * acc1[m][2] + sw * acc2[m][2] + acc3[m][2]) * inv;
    o.w = (cw * acc1[m][3] + sw * acc2[m][3] + acc3[m][3]) * inv;
    *(float4*)&attn[(size_t)(c * 64 + i) * E_DIM + h * 64 + tx * 4] = o;
  }
}

// ---------------------------------------------------------------------------
extern "C" void kernel_launch(void* const* d_in, const int* in_sizes, int n_in,
                              void* d_out, int out_size, void* d_ws, size_t ws_size,
                              hipStream_t stream) {
  (void)in_sizes; (void)n_in; (void)out_size; (void)ws_size;
  const float* x     = (const float*)d_in[0];
  const float* W_qkv = (const float*)d_in[1];
  const float* b_qkv = (const float*)d_in[2];
  const float* W_out = (const float*)d_in[3];
  const float* b_out = (const float*)d_in[4];
  float* out = (float*)d_out;

  float* ws = (float*)d_ws;
  float* qkv   = ws;                    // 2048*1536 = 3,145,728 floats
  float* S     = qkv + 3145728;         // 8*32*8192 = 2,097,152
  float* Sp    = S + 2097152;           // 2,097,152
  float* ksum  = Sp + 2097152;          // 8*32*128 = 32,768
  float* ksumP = ksum + 32768;          // 32,768
  float* attn  = ksumP + 32768;         // 2048*512 = 1,048,576

  // 1) qkv = x @ W_qkv + b_qkv   [2048 x 1536], K=512
  gemm_bias_f32<128, 8><<<dim3(12, 32), dim3(256), 0, stream>>>(
      x, W_qkv, b_qkv, qkv, L_SEQ, QKV_W, E_DIM);

  // 2) per-chunk KV sums
  chunk_kv_kernel<<<dim3(NC, H_NUM), dim3(256), 0, stream>>>(qkv, S, ksum);

  // 3) exclusive prefix scan over chunks
  scan_kernel<<<dim3(32, H_NUM), dim3(256), 0, stream>>>(S, Sp, ksum, ksumP);

  // 4) per-chunk outputs
  chunk_out_kernel<<<dim3(NC, H_NUM), dim3(256), 0, stream>>>(qkv, Sp, ksumP, attn);

  // 5) out = attn @ W_out + b_out   [2048 x 512], K=512
  gemm_bias_f32<64, 8><<<dim3(8, 32), dim3(128), 0, stream>>>(
      attn, W_out, b_out, out, L_SEQ, E_DIM, E_DIM);
}

// Round 2
// 126.981 us; speedup vs baseline: 1.7292x; 1.7292x over previous
//
#include <hip/hip_runtime.h>

// Problem constants (B=1, L=2048, E=512, H=8, D=64)
constexpr int L_SEQ = 2048;
constexpr int E_DIM = 512;
constexpr int H_NUM = 8;
constexpr int QKV_W = 3 * E_DIM;   // 1536
constexpr int CHK = 64;            // chunk length
constexpr int NC = L_SEQ / CHK;    // 32 chunks
constexpr float PI_HALF = 1.5707963267948966f;

typedef __attribute__((ext_vector_type(8))) short bf16x8;
typedef __attribute__((ext_vector_type(4))) float f32x4;
typedef __attribute__((ext_vector_type(4))) short short4v;

__device__ __forceinline__ short f2bf(float f) {
  union { float f; unsigned int u; } v; v.f = f;
  unsigned int r = v.u + 0x7fffu + ((v.u >> 16) & 1u);  // RNE
  return (short)(r >> 16);
}

__device__ __forceinline__ void glds16(const void* g, void* l) {
  __builtin_amdgcn_global_load_lds(
      (const __attribute__((address_space(1))) unsigned int*)g,
      (__attribute__((address_space(3))) unsigned int*)l, 16, 0, 0);
}

// ---------------------------------------------------------------------------
// bf16 MFMA GEMM:  C[M,N] = A[M,K](bf16) @ Bt[N,K](bf16)^T + bias[N]  (fp32 out)
// Block: 256 threads = 4 waves in 2x2 grid. Wave tile = (WTM*16) x (WTN*16).
// Block tile BM = WTM*32, BN = WTN*32. BK = 32 (one 16x16x32 MFMA per K-step).
// LDS: linear [row][k] layout (required by global_load_lds lane ordering).
// ---------------------------------------------------------------------------
template <int WTM, int WTN>
__global__ __launch_bounds__(256) void gemm_mfma_bf16(
    const short* __restrict__ A, const short* __restrict__ Bt,
    const float* __restrict__ bias, float* __restrict__ C,
    int M, int N, int K) {
  constexpr int BM = WTM * 32;
  constexpr int BN = WTN * 32;
  __shared__ short As[BM * 32];  // [r][k], 64 B per row
  __shared__ short Bs[BN * 32];  // [n][k]

  const int t = threadIdx.x;
  const int wave = t >> 6;
  const int lane = t & 63;
  const int quad = lane >> 4;
  const int lr = lane & 15;

  const int row0 = blockIdx.y * BM;
  const int col0 = blockIdx.x * BN;
  const int wrow = (wave >> 1) * (BM / 2);
  const int wcol = (wave & 1) * (BN / 2);

  f32x4 acc[WTM][WTN];
#pragma unroll
  for (int m = 0; m < WTM; ++m)
#pragma unroll
    for (int n = 0; n < WTN; ++n) acc[m][n] = (f32x4){0.f, 0.f, 0.f, 0.f};

  for (int k0 = 0; k0 < K; k0 += 32) {
    // Stage A tile (BM x 32 bf16): BM/16 wave-passes of 1024 B each.
#pragma unroll
    for (int p = wave; p < BM / 16; p += 4) {
      const int idx = p * 64 + lane;
      const int r = idx >> 2;           // 0..BM-1
      const int kq = (idx & 3) * 8;     // 0,8,16,24
      glds16(A + (size_t)(row0 + r) * K + k0 + kq, As + p * 512);
    }
    // Stage B tile (BN x 32 bf16)
#pragma unroll
    for (int p = wave; p < BN / 16; p += 4) {
      const int idx = p * 64 + lane;
      const int r = idx >> 2;
      const int kq = (idx & 3) * 8;
      glds16(Bt + (size_t)(col0 + r) * K + k0 + kq, Bs + p * 512);
    }
    __syncthreads();

    bf16x8 af[WTM], bf_[WTN];
#pragma unroll
    for (int m = 0; m < WTM; ++m)
      af[m] = *(const bf16x8*)(As + (wrow + m * 16 + lr) * 32 + quad * 8);
#pragma unroll
    for (int n = 0; n < WTN; ++n)
      bf_[n] = *(const bf16x8*)(Bs + (wcol + n * 16 + lr) * 32 + quad * 8);
#pragma unroll
    for (int m = 0; m < WTM; ++m)
#pragma unroll
      for (int n = 0; n < WTN; ++n)
        acc[m][n] = __builtin_amdgcn_mfma_f32_16x16x32_bf16(af[m], bf_[n], acc[m][n], 0, 0, 0);
    __syncthreads();
  }

  // Epilogue: C/D layout col = lane&15, row = quad*4 + reg.
#pragma unroll
  for (int m = 0; m < WTM; ++m) {
#pragma unroll
    for (int n = 0; n < WTN; ++n) {
      const int col = col0 + wcol + n * 16 + lr;
      const int rowb = row0 + wrow + m * 16 + quad * 4;
      const float bb = bias[col];
#pragma unroll
      for (int r = 0; r < 4; ++r)
        C[(size_t)(rowb + r) * N + col] = acc[m][n][r] + bb;
    }
  }
}

// ---------------------------------------------------------------------------
// Prep kernels: fp32 -> bf16 cast (x) and transpose-cast (weights -> [N,K]).
// ---------------------------------------------------------------------------
__global__ __launch_bounds__(256) void cast_x_kernel(
    const float* __restrict__ x, short* __restrict__ xb) {
  const int i = blockIdx.x * 256 + threadIdx.x;  // per float4
  const float4 v = ((const float4*)x)[i];
  short4v o;
  o.x = f2bf(v.x); o.y = f2bf(v.y); o.z = f2bf(v.z); o.w = f2bf(v.w);
  ((short4v*)xb)[i] = o;
}

__global__ __launch_bounds__(256) void transpose_cast_kernel(
    const float* __restrict__ W, short* __restrict__ Wt, int R, int Cc) {
  // W[R][Cc] -> Wt[Cc][R] (bf16). Tile 32x32.
  __shared__ float tile[32][33];
  const int c0 = blockIdx.x * 32, r0 = blockIdx.y * 32;
  const int tx = threadIdx.x & 31, ty = threadIdx.x >> 5;  // ty 0..7
  for (int i = ty; i < 32; i += 8) tile[i][tx] = W[(size_t)(r0 + i) * Cc + c0 + tx];
  __syncthreads();
  for (int i = ty; i < 32; i += 8)
    Wt[(size_t)(c0 + i) * R + r0 + tx] = f2bf(tile[tx][i]);
}

// ---------------------------------------------------------------------------
// Kernel A: per-(head, chunk) KV state sums.
// ---------------------------------------------------------------------------
__global__ __launch_bounds__(256) void chunk_kv_kernel(
    const float* __restrict__ qkv, float* __restrict__ S, float* __restrict__ ksum) {
  const int c = blockIdx.x, h = blockIdx.y;
  __shared__ float kc[64][64];   // relu(k)*cos(th_i)  [i][d]
  __shared__ float ksn[64][64];  // relu(k)*sin(th_i)
  __shared__ float vs[64][64];   // v                  [i][e]
  __shared__ float cwA[64], swA[64];
  const int t = threadIdx.x;

  for (int idx = t; idx < 4096; idx += 256) {
    const int i = idx >> 6, d = idx & 63;
    const float* row = qkv + (size_t)(c * 64 + i) * QKV_W;
    kc[i][d] = fmaxf(row[E_DIM + h * 64 + d], 0.f);
    vs[i][d] = row[2 * E_DIM + h * 64 + d];
  }
  if (t < 64) {
    const int l = c * 64 + t;
    const float th = PI_HALF * (float)l / (float)L_SEQ;
    cwA[t] = cosf(th);
    swA[t] = sinf(th);
  }
  __syncthreads();
  for (int idx = t; idx < 4096; idx += 256) {
    const int i = idx >> 6, d = idx & 63;
    const float kv_ = kc[i][d];
    ksn[i][d] = kv_ * swA[i];
    kc[i][d] = kv_ * cwA[i];
  }
  __syncthreads();

  const int tx = t & 15, ty = t >> 4;
  float acc_c[4][4], acc_s[4][4];
#pragma unroll
  for (int m = 0; m < 4; ++m)
#pragma unroll
    for (int n = 0; n < 4; ++n) { acc_c[m][n] = 0.f; acc_s[m][n] = 0.f; }

  for (int i = 0; i < 64; ++i) {
    const float4 ac = *(const float4*)&kc[i][ty * 4];
    const float4 as = *(const float4*)&ksn[i][ty * 4];
    const float4 b4 = *(const float4*)&vs[i][tx * 4];
    const float avc[4] = {ac.x, ac.y, ac.z, ac.w};
    const float avs[4] = {as.x, as.y, as.z, as.w};
    const float bv[4] = {b4.x, b4.y, b4.z, b4.w};
#pragma unroll
    for (int m = 0; m < 4; ++m)
#pragma unroll
      for (int n = 0; n < 4; ++n) {
        acc_c[m][n] += avc[m] * bv[n];
        acc_s[m][n] += avs[m] * bv[n];
      }
  }

  float* Sc = S + ((size_t)(h * NC + c)) * 8192;
#pragma unroll
  for (int m = 0; m < 4; ++m) {
    const int d = ty * 4 + m;
    float4 oc, os;
    oc.x = acc_c[m][0]; oc.y = acc_c[m][1]; oc.z = acc_c[m][2]; oc.w = acc_c[m][3];
    os.x = acc_s[m][0]; os.y = acc_s[m][1]; os.z = acc_s[m][2]; os.w = acc_s[m][3];
    *(float4*)&Sc[(size_t)d * 64 + tx * 4] = oc;
    *(float4*)&Sc[(size_t)(64 + d) * 64 + tx * 4] = os;
  }

  if (t < 64) {
    float sc = 0.f, ss = 0.f;
    for (int i = 0; i < 64; ++i) { sc += kc[i][t]; ss += ksn[i][t]; }
    float* Kc = ksum + (size_t)(h * NC + c) * 128;
    Kc[t] = sc;
    Kc[64 + t] = ss;
  }
}

// ---------------------------------------------------------------------------
// Kernel B: exclusive prefix scan over chunks.
// ---------------------------------------------------------------------------
__global__ __launch_bounds__(256) void scan_kernel(
    const float* __restrict__ S, float* __restrict__ Sp,
    const float* __restrict__ ksum, float* __restrict__ ksumP) {
  const int h = blockIdx.y;
  const int e = blockIdx.x * 256 + threadIdx.x;  // 0..8191
  float run = 0.f;
  for (int c = 0; c < NC; ++c) {
    const size_t off = ((size_t)(h * NC + c)) * 8192 + e;
    Sp[off] = run;
    run += S[off];
  }
  if (blockIdx.x == 0 && threadIdx.x < 128) {
    const int d = threadIdx.x;
    float r2 = 0.f;
    for (int c = 0; c < NC; ++c) {
      const size_t off = (size_t)(h * NC + c) * 128 + d;
      ksumP[off] = r2;
      r2 += ksum[off];
    }
  }
}

// ---------------------------------------------------------------------------
// Kernel C: per-(head, chunk) output -> attn in bf16 (feeds gemm2).
// ---------------------------------------------------------------------------
__global__ __launch_bounds__(256) void chunk_out_kernel(
    const float* __restrict__ qkv, const float* __restrict__ Sp,
    const float* __restrict__ ksumP, short* __restrict__ attn) {
  const int c = blockIdx.x, h = blockIdx.y;
  __shared__ float qs[64][65];   // relu(q) [i][d]
  __shared__ float ksA[64][65];  // relu(k) [j][d], later A[i][j]
  __shared__ float vs[64][64];   // v [j][e]
  __shared__ float cwA[64], swA[64], nrmA[64];
  const int t = threadIdx.x;

  for (int idx = t; idx < 4096; idx += 256) {
    const int i = idx >> 6, d = idx & 63;
    const float* row = qkv + (size_t)(c * 64 + i) * QKV_W;
    qs[i][d] = fmaxf(row[h * 64 + d], 0.f);
    ksA[i][d] = fmaxf(row[E_DIM + h * 64 + d], 0.f);
    vs[i][d] = row[2 * E_DIM + h * 64 + d];
  }
  if (t < 64) {
    const int l = c * 64 + t;
    const float th = PI_HALF * (float)l / (float)L_SEQ;
    cwA[t] = cosf(th);
    swA[t] = sinf(th);
  }
  __syncthreads();

  const int tx = t & 15, ty = t >> 4;
  float areg[4][4];
  {
    float acc[4][4];
#pragma unroll
    for (int m = 0; m < 4; ++m)
#pragma unroll
      for (int n = 0; n < 4; ++n) acc[m][n] = 0.f;
    for (int d = 0; d < 64; ++d) {
      float av[4], bv[4];
#pragma unroll
      for (int m = 0; m < 4; ++m) av[m] = qs[ty * 4 + m][d];
#pragma unroll
      for (int n = 0; n < 4; ++n) bv[n] = ksA[tx * 4 + n][d];
#pragma unroll
      for (int m = 0; m < 4; ++m)
#pragma unroll
        for (int n = 0; n < 4; ++n) acc[m][n] += av[m] * bv[n];
    }
#pragma unroll
    for (int m = 0; m < 4; ++m)
#pragma unroll
      for (int n = 0; n < 4; ++n) {
        const int i = ty * 4 + m, j = tx * 4 + n;
        const float w = cwA[i] * cwA[j] + swA[i] * swA[j];
        areg[m][n] = (j <= i) ? acc[m][n] * w : 0.f;
      }
  }
  __syncthreads();
#pragma unroll
  for (int m = 0; m < 4; ++m)
#pragma unroll
    for (int n = 0; n < 4; ++n) ksA[ty * 4 + m][tx * 4 + n] = areg[m][n];
  __syncthreads();

  if (t < 64) {
    const int i = t;
    const float* Kp = ksumP + (size_t)(h * NC + c) * 128;
    float s1 = 0.f, s2 = 0.f;
    for (int d = 0; d < 64; ++d) {
      const float q = qs[i][d];
      s1 += q * Kp[d];
      s2 += q * Kp[64 + d];
    }
    float s = cwA[i] * s1 + swA[i] * s2;
    for (int j = 0; j <= i; ++j) s += ksA[i][j];
    nrmA[i] = s;
  }
  __syncthreads();

  const float* Sc = Sp + ((size_t)(h * NC + c)) * 8192;
  float acc1[4][4], acc2[4][4], acc3[4][4];
#pragma unroll
  for (int m = 0; m < 4; ++m)
#pragma unroll
    for (int n = 0; n < 4; ++n) { acc1[m][n] = 0.f; acc2[m][n] = 0.f; acc3[m][n] = 0.f; }

  for (int d = 0; d < 64; ++d) {
    float av[4];
#pragma unroll
    for (int m = 0; m < 4; ++m) av[m] = qs[ty * 4 + m][d];
    const float4 b1 = *(const float4*)&Sc[(size_t)d * 64 + tx * 4];
    const float4 b2 = *(const float4*)&Sc[(size_t)(64 + d) * 64 + tx * 4];
    const float bv1[4] = {b1.x, b1.y, b1.z, b1.w};
    const float bv2[4] = {b2.x, b2.y, b2.z, b2.w};
#pragma unroll
    for (int m = 0; m < 4; ++m)
#pragma unroll
      for (int n = 0; n < 4; ++n) {
        acc1[m][n] += av[m] * bv1[n];
        acc2[m][n] += av[m] * bv2[n];
      }
  }
  for (int j = 0; j < 64; ++j) {
    float av[4];
#pragma unroll
    for (int m = 0; m < 4; ++m) av[m] = ksA[ty * 4 + m][j];
    const float4 b4 = *(const float4*)&vs[j][tx * 4];
    const float bv[4] = {b4.x, b4.y, b4.z, b4.w};
#pragma unroll
    for (int m = 0; m < 4; ++m)
#pragma unroll
      for (int n = 0; n < 4; ++n) acc3[m][n] += av[m] * bv[n];
  }

#pragma unroll
  for (int m = 0; m < 4; ++m) {
    const int i = ty * 4 + m;
    const float inv = 1.0f / (nrmA[i] + 1e-6f);
    const float cw = cwA[i], sw = swA[i];
    short4v o;
    o.x = f2bf((cw * acc1[m][0] + sw * acc2[m][0] + acc3[m][0]) * inv);
    o.y = f2bf((cw * acc1[m][1] + sw * acc2[m][1] + acc3[m][1]) * inv);
    o.z = f2bf((cw * acc1[m][2] + sw * acc2[m][2] + acc3[m][2]) * inv);
    o.w = f2bf((cw * acc1[m][3] + sw * acc2[m][3] + acc3[m][3]) * inv);
    *(short4v*)&attn[(size_t)(c * 64 + i) * E_DIM + h * 64 + tx * 4] = o;
  }
}

// ---------------------------------------------------------------------------
extern "C" void kernel_launch(void* const* d_in, const int* in_sizes, int n_in,
                              void* d_out, int out_size, void* d_ws, size_t ws_size,
                              hipStream_t stream) {
  (void)in_sizes; (void)n_in; (void)out_size; (void)ws_size;
  const float* x     = (const float*)d_in[0];
  const float* W_qkv = (const float*)d_in[1];
  const float* b_qkv = (const float*)d_in[2];
  const float* W_out = (const float*)d_in[3];
  const float* b_out = (const float*)d_in[4];
  float* out = (float*)d_out;

  float* ws = (float*)d_ws;
  float* qkv    = ws;                    // 2048*1536 = 3,145,728 f32
  float* S      = qkv + 3145728;         // 2,097,152 f32
  float* Sp     = S + 2097152;           // 2,097,152 f32
  float* ksum   = Sp + 2097152;          // 32,768 f32
  float* ksumP  = ksum + 32768;          // 32,768 f32
  short* attn_b = (short*)(ksumP + 32768);       // 2048*512 bf16 = 524,288 f32-units
  short* xb     = attn_b + 1048576;              // 2048*512 bf16
  short* Wqkv_t = xb + 1048576;                  // 1536*512 bf16
  short* Wout_t = Wqkv_t + 786432;               // 512*512 bf16

  // Prep: casts + weight transposes (independent)
  cast_x_kernel<<<1024, 256, 0, stream>>>(x, xb);
  transpose_cast_kernel<<<dim3(48, 16), 256, 0, stream>>>(W_qkv, Wqkv_t, E_DIM, QKV_W);
  transpose_cast_kernel<<<dim3(16, 16), 256, 0, stream>>>(W_out, Wout_t, E_DIM, E_DIM);

  // 1) qkv = x @ W_qkv + b_qkv  [2048 x 1536], K=512.  128x64 tiles -> 24x16=384 blocks
  gemm_mfma_bf16<4, 2><<<dim3(QKV_W / 64, L_SEQ / 128), 256, 0, stream>>>(
      xb, Wqkv_t, b_qkv, qkv, L_SEQ, QKV_W, E_DIM);

  // 2) per-chunk KV sums
  chunk_kv_kernel<<<dim3(NC, H_NUM), 256, 0, stream>>>(qkv, S, ksum);

  // 3) exclusive prefix scan over chunks
  scan_kernel<<<dim3(32, H_NUM), 256, 0, stream>>>(S, Sp, ksum, ksumP);

  // 4) per-chunk outputs -> attn (bf16)
  chunk_out_kernel<<<dim3(NC, H_NUM), 256, 0, stream>>>(qkv, Sp, ksumP, attn_b);

  // 5) out = attn @ W_out + b_out  [2048 x 512], K=512.  64x64 tiles -> 8x32=256 blocks
  gemm_mfma_bf16<2, 2><<<dim3(E_DIM / 64, L_SEQ / 64), 256, 0, stream>>>(
      attn_b, Wout_t, b_out, out, L_SEQ, E_DIM, E_DIM);
}

// Round 3
// 114.060 us; speedup vs baseline: 1.9251x; 1.1133x over previous
//
#include <hip/hip_runtime.h>

// Problem constants (B=1, L=2048, E=512, H=8, D=64)
constexpr int L_SEQ = 2048;
constexpr int E_DIM = 512;
constexpr int H_NUM = 8;
constexpr int QKV_W = 3 * E_DIM;   // 1536
constexpr int CHK = 64;            // chunk length
constexpr int NC = L_SEQ / CHK;    // 32 chunks
constexpr float PI_HALF = 1.5707963267948966f;

typedef __attribute__((ext_vector_type(8))) short bf16x8;
typedef __attribute__((ext_vector_type(4))) float f32x4;
typedef __attribute__((ext_vector_type(4))) short short4v;

__device__ __forceinline__ short f2bf(float f) {
  union { float f; unsigned int u; } v; v.f = f;
  unsigned int r = v.u + 0x7fffu + ((v.u >> 16) & 1u);  // RNE
  return (short)(r >> 16);
}
__device__ __forceinline__ float bf2f(short s) {
  union { unsigned int u; float f; } v;
  v.u = ((unsigned int)(unsigned short)s) << 16;
  return v.f;
}

__device__ __forceinline__ void glds16(const void* g, void* l) {
  __builtin_amdgcn_global_load_lds(
      (const __attribute__((address_space(1))) unsigned int*)g,
      (__attribute__((address_space(3))) unsigned int*)l, 16, 0, 0);
}

// ---------------------------------------------------------------------------
// bf16 MFMA GEMM:  C[M,N] = A[M,K](bf16) @ Bt[N,K](bf16)^T + bias[N]  (fp32 out)
// Block: 256 threads = 4 waves in 2x2 grid. Wave tile = (WTM*16) x (WTN*16).
// ---------------------------------------------------------------------------
template <int WTM, int WTN>
__global__ __launch_bounds__(256) void gemm_mfma_bf16(
    const short* __restrict__ A, const short* __restrict__ Bt,
    const float* __restrict__ bias, float* __restrict__ C,
    int M, int N, int K) {
  constexpr int BM = WTM * 32;
  constexpr int BN = WTN * 32;
  __shared__ short As[BM * 32];  // [r][k], linear (global_load_lds order)
  __shared__ short Bs[BN * 32];  // [n][k]

  const int t = threadIdx.x;
  const int wave = t >> 6;
  const int lane = t & 63;
  const int quad = lane >> 4;
  const int lr = lane & 15;

  const int row0 = blockIdx.y * BM;
  const int col0 = blockIdx.x * BN;
  const int wrow = (wave >> 1) * (BM / 2);
  const int wcol = (wave & 1) * (BN / 2);

  f32x4 acc[WTM][WTN];
#pragma unroll
  for (int m = 0; m < WTM; ++m)
#pragma unroll
    for (int n = 0; n < WTN; ++n) acc[m][n] = (f32x4){0.f, 0.f, 0.f, 0.f};

  for (int k0 = 0; k0 < K; k0 += 32) {
#pragma unroll
    for (int p = wave; p < BM / 16; p += 4) {
      const int idx = p * 64 + lane;
      const int r = idx >> 2;
      const int kq = (idx & 3) * 8;
      glds16(A + (size_t)(row0 + r) * K + k0 + kq, As + p * 512);
    }
#pragma unroll
    for (int p = wave; p < BN / 16; p += 4) {
      const int idx = p * 64 + lane;
      const int r = idx >> 2;
      const int kq = (idx & 3) * 8;
      glds16(Bt + (size_t)(col0 + r) * K + k0 + kq, Bs + p * 512);
    }
    __syncthreads();

    bf16x8 af[WTM], bf_[WTN];
#pragma unroll
    for (int m = 0; m < WTM; ++m)
      af[m] = *(const bf16x8*)(As + (wrow + m * 16 + lr) * 32 + quad * 8);
#pragma unroll
    for (int n = 0; n < WTN; ++n)
      bf_[n] = *(const bf16x8*)(Bs + (wcol + n * 16 + lr) * 32 + quad * 8);
#pragma unroll
    for (int m = 0; m < WTM; ++m)
#pragma unroll
      for (int n = 0; n < WTN; ++n)
        acc[m][n] = __builtin_amdgcn_mfma_f32_16x16x32_bf16(af[m], bf_[n], acc[m][n], 0, 0, 0);
    __syncthreads();
  }

#pragma unroll
  for (int m = 0; m < WTM; ++m) {
#pragma unroll
    for (int n = 0; n < WTN; ++n) {
      const int col = col0 + wcol + n * 16 + lr;
      const int rowb = row0 + wrow + m * 16 + quad * 4;
      const float bb = bias[col];
#pragma unroll
      for (int r = 0; r < 4; ++r)
        C[(size_t)(rowb + r) * N + col] = acc[m][n][r] + bb;
    }
  }
}

// ---------------------------------------------------------------------------
// Prep kernels
// ---------------------------------------------------------------------------
__global__ __launch_bounds__(256) void cast_x_kernel(
    const float* __restrict__ x, short* __restrict__ xb) {
  const int i = blockIdx.x * 256 + threadIdx.x;
  const float4 v = ((const float4*)x)[i];
  short4v o;
  o.x = f2bf(v.x); o.y = f2bf(v.y); o.z = f2bf(v.z); o.w = f2bf(v.w);
  ((short4v*)xb)[i] = o;
}

__global__ __launch_bounds__(256) void transpose_cast_kernel(
    const float* __restrict__ W, short* __restrict__ Wt, int R, int Cc) {
  __shared__ float tile[32][33];
  const int c0 = blockIdx.x * 32, r0 = blockIdx.y * 32;
  const int tx = threadIdx.x & 31, ty = threadIdx.x >> 5;
  for (int i = ty; i < 32; i += 8) tile[i][tx] = W[(size_t)(r0 + i) * Cc + c0 + tx];
  __syncthreads();
  for (int i = ty; i < 32; i += 8)
    Wt[(size_t)(c0 + i) * R + r0 + tx] = f2bf(tile[tx][i]);
}

// ---------------------------------------------------------------------------
// Kernel A (MFMA): per-(chunk, head) state sums.
//   S[(h,c)][e][dd] = sum_i v[i][e] * kw[i][dd]   (dd<64: cos, >=64: sin)
//   ksum[(h,c)][dd] = sum_i kw[i][dd]
// MFMA: m=e (A-op = vT[e][i]), n=dd (B-op = kT[dd][i]), k=i.
// ---------------------------------------------------------------------------
__global__ __launch_bounds__(256) void chunk_kv_mfma(
    const float* __restrict__ qkv, float* __restrict__ S, float* __restrict__ ksum) {
  const int c = blockIdx.x, h = blockIdx.y;
  __shared__ short kT[128][72];  // kw transposed [dd][i]
  __shared__ short vT[64][72];   // v transposed  [e][i]
  const int t = threadIdx.x;
  const int w = t >> 6, lane = t & 63, lr = lane & 15, quad = lane >> 4;

  // Load + transpose: idx = t + 256r -> i = w + 4r, d = lane
#pragma unroll
  for (int r = 0; r < 16; ++r) {
    const int i = w + 4 * r, d = lane;
    const float* row = qkv + (size_t)(c * 64 + i) * QKV_W;
    const float kv_ = fmaxf(row[E_DIM + h * 64 + d], 0.f);
    const float v_ = row[2 * E_DIM + h * 64 + d];
    const float th = PI_HALF * (float)(c * 64 + i) / (float)L_SEQ;
    kT[d][i] = f2bf(kv_ * __cosf(th));
    kT[64 + d][i] = f2bf(kv_ * __sinf(th));
    vT[d][i] = f2bf(v_);
  }
  __syncthreads();

  f32x4 acc[8];
#pragma unroll
  for (int n = 0; n < 8; ++n) acc[n] = (f32x4){0.f, 0.f, 0.f, 0.f};
#pragma unroll
  for (int kk = 0; kk < 2; ++kk) {
    const bf16x8 av = *(const bf16x8*)&vT[16 * w + lr][kk * 32 + quad * 8];
#pragma unroll
    for (int n = 0; n < 8; ++n) {
      const bf16x8 bv = *(const bf16x8*)&kT[16 * n + lr][kk * 32 + quad * 8];
      acc[n] = __builtin_amdgcn_mfma_f32_16x16x32_bf16(av, bv, acc[n], 0, 0, 0);
    }
  }

  float* Sc = S + ((size_t)(h * NC + c)) * 8192;  // [e][128]
#pragma unroll
  for (int n = 0; n < 8; ++n) {
    const int dd = 16 * n + lr;
#pragma unroll
    for (int r = 0; r < 4; ++r) {
      const int e = 16 * w + quad * 4 + r;
      Sc[(size_t)e * 128 + dd] = acc[n][r];
    }
  }

  // ksum from kT (threads 0..127)
  if (t < 128) {
    float s = 0.f;
#pragma unroll
    for (int j = 0; j < 8; ++j) {
      const bf16x8 kv8 = *(const bf16x8*)&kT[t][j * 8];
#pragma unroll
      for (int q = 0; q < 8; ++q) s += bf2f(kv8[q]);
    }
    ksum[(size_t)(h * NC + c) * 128 + t] = s;
  }
}

// ---------------------------------------------------------------------------
// Kernel B: exclusive prefix scan over chunks. S fp32 [e][dd] -> Spb bf16.
// ---------------------------------------------------------------------------
__global__ __launch_bounds__(256) void scan_kernel(
    const float* __restrict__ S, short* __restrict__ Spb,
    const float* __restrict__ ksum, float* __restrict__ ksumP) {
  const int h = blockIdx.y;
  const int e = blockIdx.x * 256 + threadIdx.x;  // 0..8191
  float run = 0.f;
#pragma unroll
  for (int c = 0; c < NC; ++c) {
    const size_t off = ((size_t)(h * NC + c)) * 8192 + e;
    Spb[off] = f2bf(run);
    run += S[off];
  }
  if (blockIdx.x == 0 && threadIdx.x < 128) {
    const int d = threadIdx.x;
    float r2 = 0.f;
#pragma unroll
    for (int c = 0; c < NC; ++c) {
      const size_t off = (size_t)(h * NC + c) * 128 + d;
      ksumP[off] = r2;
      r2 += ksum[off];
    }
  }
}

// ---------------------------------------------------------------------------
// Kernel C (MFMA): per-(chunk, head) output -> attn bf16.
//   Qcat[i][dd] = relu(q)[i][d] * (cw|sw)[i];  Kcat likewise.
//   A = Qcat @ Kcat^T  (masked j<=i)           [intra scores, weight folded]
//   ctx = Qcat @ Spb^T + Am @ vT^T
//   nrm = rowsum(Am) (fp32 via shfl) + Qcat . ksumP
// ---------------------------------------------------------------------------
__global__ __launch_bounds__(256) void chunk_out_mfma(
    const float* __restrict__ qkv, const short* __restrict__ Spb,
    const float* __restrict__ ksumP, short* __restrict__ attn) {
  const int c = blockIdx.x, h = blockIdx.y;
  __shared__ short Qc[64][136];
  __shared__ short Kc[64][136];
  __shared__ short Am[64][72];
  __shared__ short vT[64][72];
  __shared__ float nrmP[64][4];
  __shared__ float nrmA[64];
  const int t = threadIdx.x;
  const int w = t >> 6, lane = t & 63, lr = lane & 15, quad = lane >> 4;

  // Load phase: i = w + 4r, d = lane
#pragma unroll
  for (int r = 0; r < 16; ++r) {
    const int i = w + 4 * r, d = lane;
    const float* row = qkv + (size_t)(c * 64 + i) * QKV_W;
    const float q_ = fmaxf(row[h * 64 + d], 0.f);
    const float k_ = fmaxf(row[E_DIM + h * 64 + d], 0.f);
    const float v_ = row[2 * E_DIM + h * 64 + d];
    const float th = PI_HALF * (float)(c * 64 + i) / (float)L_SEQ;
    const float cw = __cosf(th), sw = __sinf(th);
    Qc[i][d] = f2bf(q_ * cw);
    Qc[i][64 + d] = f2bf(q_ * sw);
    Kc[i][d] = f2bf(k_ * cw);
    Kc[i][64 + d] = f2bf(k_ * sw);
    vT[d][i] = f2bf(v_);
  }
  __syncthreads();

  // Step 2: A = Qcat @ Kcat^T  (m-tile = w, n-tiles 0..3, K=128)
  f32x4 acc_a[4];
#pragma unroll
  for (int n = 0; n < 4; ++n) acc_a[n] = (f32x4){0.f, 0.f, 0.f, 0.f};
#pragma unroll
  for (int kk = 0; kk < 4; ++kk) {
    const bf16x8 av = *(const bf16x8*)&Qc[16 * w + lr][kk * 32 + quad * 8];
#pragma unroll
    for (int n = 0; n < 4; ++n) {
      const bf16x8 bv = *(const bf16x8*)&Kc[16 * n + lr][kk * 32 + quad * 8];
      acc_a[n] = __builtin_amdgcn_mfma_f32_16x16x32_bf16(av, bv, acc_a[n], 0, 0, 0);
    }
  }
  // Mask, row-sum (fp32, shfl over the 16 lanes of each row), write Am bf16
#pragma unroll
  for (int n = 0; n < 4; ++n) {
#pragma unroll
    for (int r = 0; r < 4; ++r) {
      const int gi = 16 * w + quad * 4 + r;
      const int gj = 16 * n + lr;
      float val = (gj <= gi) ? acc_a[n][r] : 0.f;
      Am[gi][gj] = f2bf(val);
      float s = val;
      s += __shfl_xor(s, 1, 64);
      s += __shfl_xor(s, 2, 64);
      s += __shfl_xor(s, 4, 64);
      s += __shfl_xor(s, 8, 64);
      if (lr == 0) nrmP[gi][n] = s;
    }
  }

  // Step 3: ctx_inter = Qcat @ Spb^T (B-frags straight from global)
  const short* Spc = Spb + ((size_t)(h * NC + c)) * 8192;  // [e][128]
  f32x4 acc_c[4];
#pragma unroll
  for (int n = 0; n < 4; ++n) acc_c[n] = (f32x4){0.f, 0.f, 0.f, 0.f};
#pragma unroll
  for (int kk = 0; kk < 4; ++kk) {
    const bf16x8 av = *(const bf16x8*)&Qc[16 * w + lr][kk * 32 + quad * 8];
#pragma unroll
    for (int n = 0; n < 4; ++n) {
      const bf16x8 bv = *(const bf16x8*)(Spc + (size_t)(16 * n + lr) * 128 + kk * 32 + quad * 8);
      acc_c[n] = __builtin_amdgcn_mfma_f32_16x16x32_bf16(av, bv, acc_c[n], 0, 0, 0);
    }
  }
  __syncthreads();  // Am, nrmP visible

  // Step 5: ctx_intra += Am @ vT^T (K=64 over j)
#pragma unroll
  for (int kk = 0; kk < 2; ++kk) {
    const bf16x8 av = *(const bf16x8*)&Am[16 * w + lr][kk * 32 + quad * 8];
#pragma unroll
    for (int n = 0; n < 4; ++n) {
      const bf16x8 bv = *(const bf16x8*)&vT[16 * n + lr][kk * 32 + quad * 8];
      acc_c[n] = __builtin_amdgcn_mfma_f32_16x16x32_bf16(av, bv, acc_c[n], 0, 0, 0);
    }
  }

  // Step 6: nrm inter-dot: thread (i = t>>2, p = t&3) handles 32 dd
  {
    const int i = t >> 2, p = t & 3;
    const float* Kp = ksumP + (size_t)(h * NC + c) * 128;
    float dot = 0.f;
#pragma unroll
    for (int jj = 0; jj < 32; ++jj) {
      const int dd = p * 32 + jj;
      dot += bf2f(Qc[i][dd]) * Kp[dd];
    }
    nrmP[i][p] += dot;
  }
  __syncthreads();
  if (t < 64) nrmA[t] = nrmP[t][0] + nrmP[t][1] + nrmP[t][2] + nrmP[t][3];
  __syncthreads();

  // Epilogue
#pragma unroll
  for (int n = 0; n < 4; ++n) {
#pragma unroll
    for (int r = 0; r < 4; ++r) {
      const int gi = 16 * w + quad * 4 + r;
      const int e = 16 * n + lr;
      const float val = acc_c[n][r] / (nrmA[gi] + 1e-6f);
      attn[(size_t)(c * 64 + gi) * E_DIM + h * 64 + e] = f2bf(val);
    }
  }
}

// ---------------------------------------------------------------------------
extern "C" void kernel_launch(void* const* d_in, const int* in_sizes, int n_in,
                              void* d_out, int out_size, void* d_ws, size_t ws_size,
                              hipStream_t stream) {
  (void)in_sizes; (void)n_in; (void)out_size; (void)ws_size;
  const float* x     = (const float*)d_in[0];
  const float* W_qkv = (const float*)d_in[1];
  const float* b_qkv = (const float*)d_in[2];
  const float* W_out = (const float*)d_in[3];
  const float* b_out = (const float*)d_in[4];
  float* out = (float*)d_out;

  float* ws = (float*)d_ws;
  float* qkv    = ws;                      // 3,145,728 f32
  float* S      = qkv + 3145728;           // 2,097,152 f32  [hc][e][dd]
  float* ksum   = S + 2097152;             // 32,768 f32
  float* ksumP  = ksum + 32768;            // 32,768 f32
  short* Spb    = (short*)(ksumP + 32768); // 2,097,152 bf16
  short* attn_b = Spb + 2097152;           // 1,048,576 bf16
  short* xb     = attn_b + 1048576;        // 1,048,576 bf16
  short* Wqkv_t = xb + 1048576;            // 786,432 bf16
  short* Wout_t = Wqkv_t + 786432;         // 262,144 bf16

  cast_x_kernel<<<1024, 256, 0, stream>>>(x, xb);
  transpose_cast_kernel<<<dim3(48, 16), 256, 0, stream>>>(W_qkv, Wqkv_t, E_DIM, QKV_W);
  transpose_cast_kernel<<<dim3(16, 16), 256, 0, stream>>>(W_out, Wout_t, E_DIM, E_DIM);

  // 1) qkv = x @ W_qkv + b_qkv  [2048x1536], K=512. 128x128 tiles -> 12x16=192 blocks
  gemm_mfma_bf16<4, 4><<<dim3(QKV_W / 128, L_SEQ / 128), 256, 0, stream>>>(
      xb, Wqkv_t, b_qkv, qkv, L_SEQ, QKV_W, E_DIM);

  // 2) per-chunk KV sums (MFMA)
  chunk_kv_mfma<<<dim3(NC, H_NUM), 256, 0, stream>>>(qkv, S, ksum);

  // 3) exclusive prefix scan over chunks (-> bf16 Sp)
  scan_kernel<<<dim3(32, H_NUM), 256, 0, stream>>>(S, Spb, ksum, ksumP);

  // 4) per-chunk outputs (MFMA) -> attn bf16
  chunk_out_mfma<<<dim3(NC, H_NUM), 256, 0, stream>>>(qkv, Spb, ksumP, attn_b);

  // 5) out = attn @ W_out + b_out  [2048x512], K=512. 64x64 tiles -> 8x32=256 blocks
  gemm_mfma_bf16<2, 2><<<dim3(E_DIM / 64, L_SEQ / 64), 256, 0, stream>>>(
      attn_b, Wout_t, b_out, out, L_SEQ, E_DIM, E_DIM);
}